// Round 1
// 679.823 us; speedup vs baseline: 1.0058x; 1.0058x over previous
//
#include <hip/hip_runtime.h>

// Problem constants
constexpr int BQ = 512, CQ = 200, EQ = 128, CV = 384, KD = 384;
constexpr int M = BQ * CQ;                  // 102400 rows
constexpr int BM = 128, BN = 384, BK = 64;  // fused GEMM tile: full CV per block

using frag = __attribute__((ext_vector_type(8))) short;  // 8 bf16 (4 VGPRs)
using facc = __attribute__((ext_vector_type(4))) float;  // 4 f32 acc

// round-to-nearest-even f32 -> bf16 bits (inputs finite)
__device__ __forceinline__ short f2b(float f) {
    unsigned int u = __float_as_uint(f);
    u = (u + 0x7fffu + ((u >> 16) & 1u)) >> 16;
    return (short)u;
}
__device__ __forceinline__ unsigned pack2(float lo, float hi) {
    return (unsigned)(unsigned short)f2b(lo) | ((unsigned)(unsigned short)f2b(hi) << 16);
}

__device__ __forceinline__ float tanh_fast(float x) {
    float e = __expf(2.0f * x);
    return 1.0f - 2.0f * __builtin_amdgcn_rcpf(e + 1.0f);
}

// async global->LDS, 16B per lane; LDS dst is wave-uniform base + lane*16
__device__ __forceinline__ void async16(const void* g, void* l) {
    __builtin_amdgcn_global_load_lds(
        (const __attribute__((address_space(1))) void*)g,
        (__attribute__((address_space(3))) void*)l, 16, 0, 0);
}

// ---- K0: W f32 -> bf16 ----
__global__ __launch_bounds__(256) void conv_w(const float* __restrict__ W, short* __restrict__ Wb) {
    int i = (blockIdx.x * 256 + threadIdx.x) * 4;
    float4 v = *(const float4*)(W + i);
    uint2 o;
    o.x = pack2(v.x, v.y);
    o.y = pack2(v.z, v.w);
    *(uint2*)(Wb + i) = o;
}

// ---- K1: fused gather + convert + GEMM h = tanh(ctx @ Wb^T) + full scores ----
// grid = M/BM = 800 blocks, 512 threads (8 waves as 2m x 4n; wave tile 64x96)
__global__ __launch_bounds__(512, 2) void fused_gemm(
    const int* __restrict__ starts, const int* __restrict__ paths, const int* __restrict__ ends,
    const float* __restrict__ node_emb, const float* __restrict__ path_emb,
    const short* __restrict__ Wb, const float* __restrict__ a,
    short* __restrict__ h_out, float* __restrict__ scores)
{
    __shared__ short As[BM * BK];  // 16 KB, XOR-swizzled 16B chunks
    __shared__ short Bs[BN * BK];  // 48 KB, same swizzle (total 64 KB exactly)

    const int tid = threadIdx.x;
    const int m0 = blockIdx.x * BM;
    const int wave = tid >> 6, lane = tid & 63;
    const int wm = (wave >> 2) * 64;   // {0,64}
    const int wn = (wave & 3) * 96;    // {0,96,192,288} (multiples of 8 -> swizzle row&7==l15&7 holds)
    const int l15 = lane & 15, quad = lane >> 4;

    // A staging: 4 threads per row, each loads 16 f32 (64 B) of the selected embedding half
    const int tr = tid >> 2, part = tid & 3;
    const int grow = m0 + tr;
    const float* baseS = node_emb + (size_t)starts[grow] * EQ + part * 16;
    const float* baseP = path_emb + (size_t)paths[grow] * EQ + part * 16;
    const float* baseE = node_emb + (size_t)ends[grow]  * EQ + part * 16;
    // LDS write offsets (shorts), chunk c16 stored at slot c16 ^ (row&7)
    const int wa0 = tr * BK + (((part * 2)     ^ (tr & 7)) * 8);
    const int wa1 = tr * BK + (((part * 2 + 1) ^ (tr & 7)) * 8);

    // B staging via global_load_lds: pre-swizzled global source, linear LDS dest
    const int sr = lane >> 3;                  // row-in-8-group
    const int scb = ((lane & 7) ^ sr) * 16;    // swizzled 16B chunk in 128B row
    const char* cB = (const char*)Wb;

    facc acc[4][6];
#pragma unroll
    for (int i = 0; i < 4; ++i)
#pragma unroll
        for (int j = 0; j < 6; ++j) acc[i][j] = (facc){0.f, 0.f, 0.f, 0.f};

#pragma unroll
    for (int kc = 0; kc < 6; ++kc) {
        __syncthreads();   // previous tile's readers done
        // B slice [384 x 64]: 48 x 1KB async copies, 6 per wave
#pragma unroll
        for (int t = 0; t < 6; ++t) {
            const int r0 = wave * 48 + t * 8;
            async16(cB + ((size_t)(r0 + sr) * KD + kc * BK) * 2 + scb, &Bs[r0 * BK]);
        }
        // A slice [128 x 64]: gather f32, convert, swizzled ds_write
        const float* ap = (kc < 2 ? baseS : (kc < 4 ? baseP : baseE)) + (kc & 1) * 64;
        const float4 v0 = ((const float4*)ap)[0];
        const float4 v1 = ((const float4*)ap)[1];
        const float4 v2 = ((const float4*)ap)[2];
        const float4 v3 = ((const float4*)ap)[3];
        uint4 c0, c1;
        c0.x = pack2(v0.x, v0.y); c0.y = pack2(v0.z, v0.w);
        c0.z = pack2(v1.x, v1.y); c0.w = pack2(v1.z, v1.w);
        c1.x = pack2(v2.x, v2.y); c1.y = pack2(v2.z, v2.w);
        c1.z = pack2(v3.x, v3.y); c1.w = pack2(v3.z, v3.w);
        *(uint4*)&As[wa0] = c0;
        *(uint4*)&As[wa1] = c1;
        __syncthreads();   // drains vmcnt (async16) + lgkm (ds_write)

#pragma unroll
        for (int ks = 0; ks < 2; ++ks) {
            const int co = ((ks * 4 + quad) ^ (l15 & 7)) * 8;
            frag af[4], bf[6];
#pragma unroll
            for (int i = 0; i < 4; ++i)
                af[i] = *(const frag*)&As[(wm + i * 16 + l15) * BK + co];
#pragma unroll
            for (int j = 0; j < 6; ++j)
                bf[j] = *(const frag*)&Bs[(wn + j * 16 + l15) * BK + co];
#pragma unroll
            for (int i = 0; i < 4; ++i)
#pragma unroll
                for (int j = 0; j < 6; ++j)
                    acc[i][j] = __builtin_amdgcn_mfma_f32_16x16x32_bf16(af[i], bf[j], acc[i][j], 0, 0, 0);
        }
    }

    // ---- epilogue: tanh, store h bf16, full per-row score via cross-wave reduce
    __syncthreads();                 // all LDS reads done; reuse As as f32 scratch
    float* sp = (float*)As;          // [4 n-wave slabs][128 rows]

    float av[6];
#pragma unroll
    for (int j = 0; j < 6; ++j) av[j] = a[wn + j * 16 + l15];

#pragma unroll
    for (int i = 0; i < 4; ++i) {
        float sct[4] = {0.f, 0.f, 0.f, 0.f};
#pragma unroll
        for (int j = 0; j < 6; ++j) {
            const int col = wn + j * 16 + l15;
#pragma unroll
            for (int r = 0; r < 4; ++r) {
                const int rowo = m0 + wm + i * 16 + quad * 4 + r;
                const float hv = tanh_fast(acc[i][j][r]);
                h_out[(size_t)rowo * CV + col] = f2b(hv);
                sct[r] = fmaf(hv, av[j], sct[r]);
            }
        }
#pragma unroll
        for (int r = 0; r < 4; ++r) {
            float v = sct[r];
            v += __shfl_xor(v, 1);
            v += __shfl_xor(v, 2);
            v += __shfl_xor(v, 4);
            v += __shfl_xor(v, 8);
            if (l15 == 0)
                sp[(wave & 3) * BM + wm + i * 16 + quad * 4 + r] = v;
        }
    }
    __syncthreads();
    if (tid < BM)
        scores[m0 + tid] = sp[tid] + sp[BM + tid] + sp[2 * BM + tid] + sp[3 * BM + tid];
}

// ---- K2: per-batch softmax over C=200 + attention-weighted sum -> out[b][v] ----
__global__ __launch_bounds__(256) void c2v_attn_out(
    const float* __restrict__ scores, const short* __restrict__ h,
    float* __restrict__ out)
{
    __shared__ float attn_s[CQ];
    __shared__ float wred[4];

    const int b = blockIdx.x;
    const int t = threadIdx.x;
    const int lane = t & 63, wv = t >> 6;

    float s = -1e30f;
    if (t < CQ) s = scores[b * CQ + t];
    float m = s;
#pragma unroll
    for (int o = 32; o; o >>= 1) m = fmaxf(m, __shfl_xor(m, o));
    if (lane == 0) wred[wv] = m;
    __syncthreads();
    const float gm = fmaxf(fmaxf(wred[0], wred[1]), fmaxf(wred[2], wred[3]));
    __syncthreads();

    float e = (t < CQ) ? __expf(s - gm) : 0.0f;
    float sum = e;
#pragma unroll
    for (int o = 32; o; o >>= 1) sum += __shfl_xor(sum, o);
    if (lane == 0) wred[wv] = sum;
    __syncthreads();
    const float gs = wred[0] + wred[1] + wred[2] + wred[3];
    if (t < CQ) attn_s[t] = e / gs;
    __syncthreads();

    if (t < 192) {
        const short* hp = h + (size_t)b * CQ * CV + 2 * t;
        float a0 = 0.f, a1 = 0.f;
#pragma unroll 4
        for (int c = 0; c < CQ; ++c) {
            unsigned int u = *(const unsigned int*)hp;
            hp += CV;
            const float w = attn_s[c];
            a0 = fmaf(__uint_as_float(u << 16), w, a0);
            a1 = fmaf(__uint_as_float(u & 0xffff0000u), w, a1);
        }
        out[b * CV + 2 * t]     = a0;
        out[b * CV + 2 * t + 1] = a1;
    }
}

extern "C" void kernel_launch(void* const* d_in, const int* in_sizes, int n_in,
                              void* d_out, int out_size, void* d_ws, size_t ws_size,
                              hipStream_t stream) {
    const int*   starts   = (const int*)d_in[0];
    const int*   paths    = (const int*)d_in[1];
    const int*   ends     = (const int*)d_in[2];
    // d_in[3] = masks: unused (as in reference)
    const float* node_emb = (const float*)d_in[4];
    const float* path_emb = (const float*)d_in[5];
    const float* W        = (const float*)d_in[6];
    const float* a        = (const float*)d_in[7];
    float* out = (float*)d_out;

    // ws layout: h bf16 [M*CV] | Wb bf16 [CV*KD] | scores f32 [M]
    char* p = (char*)d_ws;
    short* h_ws = (short*)p;  p += (size_t)M * CV * sizeof(short);
    short* Wb   = (short*)p;  p += (size_t)CV * KD * sizeof(short);
    float* scores = (float*)p;

    conv_w<<<(CV * KD) / 1024, 256, 0, stream>>>(W, Wb);
    fused_gemm<<<M / BM, 512, 0, stream>>>(starts, paths, ends, node_emb, path_emb,
                                           Wb, a, h_ws, scores);
    c2v_attn_out<<<BQ, 256, 0, stream>>>(scores, h_ws, out);
}